// Round 4
// baseline (3113.836 us; speedup 1.0000x reference)
//
#include <hip/hip_runtime.h>
#include <math.h>

// Kuramoto Euler integration, N=4096, 50 steps, exploiting K symmetry.
// coupling_i = cos(th_i)*(K@sin th)_i - sin(th_i)*(K@cos th)_i
// K -> bf16 once (32 MiB). Per step: read only upper-triangular 128x128
// tiles (528 tiles = 16.5 MiB). Each off-diag tile contributes to BOTH its
// row-range (direct) and col-range (transpose, K[c,r]=K[r,c]). Tile staged
// in LDS as fp32 with pitch 129 -> both access patterns conflict-free, no
// shuffles. Partial sums via device-scope float atomicAdd into accS/accC.
// Last finishing block does the theta update + sincos + acc zeroing
// (threadfence + acq_rel counter), keeping ONE kernel per step.

#define NOSC 4096
#define TILE 128
#define NPAN 32              // NOSC / TILE
#define NACT 528             // NPAN*(NPAN+1)/2 active (upper-tri) tiles
#define NSTEPS 50
#define DTF 0.01f
#define PITCH 129            // fp32 LDS pitch: (129*r + c) % 32 conflict-safe

__device__ __forceinline__ float bflo(unsigned int u) {
  return __uint_as_float(u << 16);
}
__device__ __forceinline__ float bfhi(unsigned int u) {
  return __uint_as_float(u & 0xFFFF0000u);
}

__global__ __launch_bounds__(256) void k_init(
    const float* __restrict__ phases, float* __restrict__ theta,
    float* __restrict__ svec, float* __restrict__ cvec,
    float* __restrict__ accS, float* __restrict__ accC,
    unsigned int* __restrict__ cnt) {
  int i = blockIdx.x * blockDim.x + threadIdx.x;
  if (i < NOSC) {
    float t = phases[i];
    theta[i] = t;
    svec[i] = sinf(t);
    cvec[i] = cosf(t);
    accS[i] = 0.f;
    accC[i] = 0.f;
  }
  if (i == 0) *cnt = 0u;
}

// fp32 -> bf16 (RNE)
__global__ __launch_bounds__(256) void k_convert(
    const float4* __restrict__ K4, ushort4* __restrict__ Kb) {
  const int n4 = NOSC * NOSC / 4;
  for (int i = blockIdx.x * blockDim.x + threadIdx.x; i < n4;
       i += gridDim.x * blockDim.x) {
    float4 f = K4[i];
    ushort4 o;
    unsigned int b;
    b = __float_as_uint(f.x); b += 0x7FFFu + ((b >> 16) & 1u); o.x = (unsigned short)(b >> 16);
    b = __float_as_uint(f.y); b += 0x7FFFu + ((b >> 16) & 1u); o.y = (unsigned short)(b >> 16);
    b = __float_as_uint(f.z); b += 0x7FFFu + ((b >> 16) & 1u); o.z = (unsigned short)(b >> 16);
    b = __float_as_uint(f.w); b += 0x7FFFu + ((b >> 16) & 1u); o.w = (unsigned short)(b >> 16);
    Kb[i] = o;
  }
}

__global__ __launch_bounds__(256, 2) void k_tiles(
    const unsigned short* __restrict__ Kb, const float* __restrict__ omegas,
    float* __restrict__ theta, float* __restrict__ svec,
    float* __restrict__ cvec, float* __restrict__ accS,
    float* __restrict__ accC, unsigned int* __restrict__ cnt) {
  const int bi = blockIdx.y;   // row panel
  const int bj = blockIdx.x;   // col panel
  if (bj < bi) return;         // upper triangle only
  const bool diag = (bi == bj);

  __shared__ float tile[TILE * PITCH];           // 66048 B
  __shared__ float sv_c[TILE], cv_c[TILE];       // f over col range C_j
  __shared__ float sv_r[TILE], cv_r[TILE];       // f over row range R_i
  __shared__ float colS[TILE], colC[TILE];
  __shared__ unsigned int isLast;

  const int t = threadIdx.x;
  const int lane = t & 63;
  const int wv = t >> 6;

  if (t < TILE) {
    sv_c[t] = svec[bj * TILE + t];
    cv_c[t] = cvec[bj * TILE + t];
  } else {
    int i = t - TILE;
    sv_r[i] = svec[bi * TILE + i];
    cv_r[i] = cvec[bi * TILE + i];
  }

  // stage tile: 128 rows x 128 bf16; 2048 x 16B loads, convert to fp32 LDS
  const unsigned short* gbase =
      Kb + (size_t)(bi * TILE) * NOSC + (size_t)(bj * TILE);
  #pragma unroll
  for (int q = 0; q < 8; ++q) {
    const int idx = q * 256 + t;        // 0..2047
    const int tr = idx >> 4;            // 0..127
    const int tc = (idx & 15) << 3;     // 0,8,..,120
    const uint4 u =
        *reinterpret_cast<const uint4*>(gbase + (size_t)tr * NOSC + tc);
    float* dst = &tile[tr * PITCH + tc];
    dst[0] = bflo(u.x); dst[1] = bfhi(u.x);
    dst[2] = bflo(u.y); dst[3] = bfhi(u.y);
    dst[4] = bflo(u.z); dst[5] = bfhi(u.z);
    dst[6] = bflo(u.w); dst[7] = bfhi(u.w);
  }
  __syncthreads();

  float dS0 = 0.f, dC0 = 0.f, dS1 = 0.f, dC1 = 0.f;
  if (wv < 2) {
    if (!diag) {
      // transpose contribution ("Dot A"): out[c in C_j] += K[r,c]*f(r).
      // lane owns cols {lane, lane+64}; wave wv covers rows wv*64..+64.
      const int r0 = wv * 64;
      #pragma unroll 8
      for (int r = r0; r < r0 + 64; ++r) {
        const float fs = sv_r[r];
        const float fc = cv_r[r];
        const float k0 = tile[r * PITCH + lane];        // consecutive words
        const float k1 = tile[r * PITCH + lane + 64];
        dS0 = fmaf(k0, fs, dS0); dC0 = fmaf(k0, fc, dC0);
        dS1 = fmaf(k1, fs, dS1); dC1 = fmaf(k1, fc, dC1);
      }
    }
  } else {
    // direct contribution ("Dot B"): out[r in R_i] += K[r,c]*f(c).
    // lane owns row (wv-2)*64+lane; streams all 128 cols.
    const int r = (wv - 2) * 64 + lane;
    const float* tp = &tile[r * PITCH];   // bank (r%32 + c)%32: 2-way max
    #pragma unroll 8
    for (int c = 0; c < TILE; ++c) {
      const float k = tp[c];
      dS0 = fmaf(k, sv_c[c], dS0);
      dC0 = fmaf(k, cv_c[c], dC0);
    }
  }

  if (!diag && wv == 0) {
    colS[lane] = dS0; colC[lane] = dC0;
    colS[lane + 64] = dS1; colC[lane + 64] = dC1;
  }
  __syncthreads();

  if (!diag && wv == 1) {
    atomicAdd(&accS[bj * TILE + lane], colS[lane] + dS0);
    atomicAdd(&accC[bj * TILE + lane], colC[lane] + dC0);
    atomicAdd(&accS[bj * TILE + lane + 64], colS[lane + 64] + dS1);
    atomicAdd(&accC[bj * TILE + lane + 64], colC[lane + 64] + dC1);
  } else if (wv >= 2) {
    const int r = (wv - 2) * 64 + lane;
    atomicAdd(&accS[bi * TILE + r], dS0);
    atomicAdd(&accC[bi * TILE + r], dC0);
  }

  // ---- last-block finalize: theta update + sincos + zero accumulators
  __threadfence();
  if (t == 0) {
    unsigned int prev = __hip_atomic_fetch_add(cnt, 1u, __ATOMIC_ACQ_REL,
                                               __HIP_MEMORY_SCOPE_AGENT);
    isLast = (prev == NACT - 1) ? 1u : 0u;
  }
  __syncthreads();
  if (isLast) {
    __threadfence();
    #pragma unroll
    for (int k = 0; k < NOSC / 256; ++k) {
      const int i = k * 256 + t;
      const float aS = __hip_atomic_load(&accS[i], __ATOMIC_RELAXED,
                                         __HIP_MEMORY_SCOPE_AGENT);
      const float aC = __hip_atomic_load(&accC[i], __ATOMIC_RELAXED,
                                         __HIP_MEMORY_SCOPE_AGENT);
      const float si = svec[i];
      const float ci = cvec[i];
      const float th = theta[i] + DTF * (omegas[i] + ci * aS - si * aC);
      theta[i] = th;
      svec[i] = sinf(th);
      cvec[i] = cosf(th);
      accS[i] = 0.f;
      accC[i] = 0.f;
    }
    if (t == 0) *cnt = 0u;   // ready for next step's kernel (stream-ordered)
  }
}

// ---- fallback (ws too small for bf16 K): fp32 full-matrix step, 2 rows/wave
__global__ __launch_bounds__(256, 2) void k_step_full(
    const float* __restrict__ Kf, const float* __restrict__ omegas,
    float* __restrict__ theta,
    const float* __restrict__ s_in, const float* __restrict__ c_in,
    float* __restrict__ s_out, float* __restrict__ c_out) {
  const int lane = threadIdx.x & 63;
  const int wave = threadIdx.x >> 6;
  const int row0 = (blockIdx.x << 3) + (wave << 1);
  const int row1 = row0 + 1;
  const float4* s4 = reinterpret_cast<const float4*>(s_in);
  const float4* c4 = reinterpret_cast<const float4*>(c_in);
  const float4* K40 = reinterpret_cast<const float4*>(Kf + (size_t)row0 * NOSC);
  const float4* K41 = reinterpret_cast<const float4*>(Kf + (size_t)row1 * NOSC);
  float aS0 = 0.f, aC0 = 0.f, aS1 = 0.f, aC1 = 0.f;
  #pragma unroll
  for (int ch = 0; ch < 16; ++ch) {
    const int idx = (ch << 6) + lane;
    float4 k0 = K40[idx], k1 = K41[idx], sv = s4[idx], cv = c4[idx];
    aS0 = fmaf(k0.x, sv.x, aS0); aS0 = fmaf(k0.y, sv.y, aS0);
    aS0 = fmaf(k0.z, sv.z, aS0); aS0 = fmaf(k0.w, sv.w, aS0);
    aC0 = fmaf(k0.x, cv.x, aC0); aC0 = fmaf(k0.y, cv.y, aC0);
    aC0 = fmaf(k0.z, cv.z, aC0); aC0 = fmaf(k0.w, cv.w, aC0);
    aS1 = fmaf(k1.x, sv.x, aS1); aS1 = fmaf(k1.y, sv.y, aS1);
    aS1 = fmaf(k1.z, sv.z, aS1); aS1 = fmaf(k1.w, sv.w, aS1);
    aC1 = fmaf(k1.x, cv.x, aC1); aC1 = fmaf(k1.y, cv.y, aC1);
    aC1 = fmaf(k1.z, cv.z, aC1); aC1 = fmaf(k1.w, cv.w, aC1);
  }
  #pragma unroll
  for (int off = 32; off > 0; off >>= 1) {
    aS0 += __shfl_xor(aS0, off); aC0 += __shfl_xor(aC0, off);
    aS1 += __shfl_xor(aS1, off); aC1 += __shfl_xor(aC1, off);
  }
  const int myRow = (lane == 0) ? row0 : ((lane == 1) ? row1 : -1);
  if (myRow >= 0) {
    const float accS = (lane == 0) ? aS0 : aS1;
    const float accC = (lane == 0) ? aC0 : aC1;
    const float tn = theta[myRow] +
        DTF * (omegas[myRow] + c_in[myRow] * accS - s_in[myRow] * accC);
    theta[myRow] = tn;
    s_out[myRow] = sinf(tn);
    c_out[myRow] = cosf(tn);
  }
}

extern "C" void kernel_launch(void* const* d_in, const int* in_sizes, int n_in,
                              void* d_out, int out_size, void* d_ws, size_t ws_size,
                              hipStream_t stream) {
  const float* phases = (const float*)d_in[0];
  const float* Kmat   = (const float*)d_in[1];
  const float* omegas = (const float*)d_in[2];
  float* out = (float*)d_out;

  float* ws = (float*)d_ws;
  float* theta = ws + 0 * NOSC;
  float* svec  = ws + 1 * NOSC;
  float* cvec  = ws + 2 * NOSC;
  float* accS  = ws + 3 * NOSC;
  float* accC  = ws + 4 * NOSC;
  unsigned int* cnt = (unsigned int*)(ws + 5 * NOSC);

  const size_t headBytes = (size_t)5 * NOSC * sizeof(float) + 256;
  const size_t kbOff = (headBytes + 255) & ~(size_t)255;
  const size_t kbBytes = (size_t)NOSC * NOSC * 2;
  const bool useTiles = (ws_size >= kbOff + kbBytes);
  unsigned short* Kb = (unsigned short*)((char*)d_ws + kbOff);

  k_init<<<NOSC / 256, 256, 0, stream>>>(phases, theta, svec, cvec, accS, accC, cnt);

  if (useTiles) {
    k_convert<<<2048, 256, 0, stream>>>((const float4*)Kmat, (ushort4*)Kb);
    for (int t = 0; t < NSTEPS; ++t) {
      k_tiles<<<dim3(NPAN, NPAN), 256, 0, stream>>>(
          Kb, omegas, theta, svec, cvec, accS, accC, cnt);
    }
  } else {
    // fallback: fp32 full matrix, double-buffered s/c (reuse accS/accC)
    float* sb[2] = {svec, accS};
    float* cb[2] = {cvec, accC};
    for (int t = 0; t < NSTEPS; ++t) {
      k_step_full<<<NOSC / 8, 256, 0, stream>>>(
          Kmat, omegas, theta, sb[t & 1], cb[t & 1], sb[(t + 1) & 1], cb[(t + 1) & 1]);
    }
  }
  hipMemcpyAsync(out, theta, NOSC * sizeof(float), hipMemcpyDeviceToDevice,
                 stream);
}

// Round 5
// 469.953 us; speedup vs baseline: 6.6258x; 6.6258x over previous
//
#include <hip/hip_runtime.h>
#include <math.h>

// Kuramoto Euler integration, N=4096, 50 steps, exploiting K symmetry.
// coupling_i = cos(th_i)*(K@sin th)_i - sin(th_i)*(K@cos th)_i
// K -> bf16 once, repacked into contiguous upper-tri 128x128 tiles
// (528 tiles = 16.5 MiB/step instead of 32). Each step = 2 kernels:
//   k_tiles : 528 blocks, one tile each; LDS-staged tile (pitch-67 words,
//             both access orders <=2-way conflict); computes direct (row)
//             and transpose (col) dots; plain stores into disjoint slots of
//             part[32][2][4096]. No atomics, no fences.
//   k_reduce: sums 32 slots per output, theta update + sincos.
// Cross-kernel visibility via stream ordering only.

#define NOSC 4096
#define TILE 128
#define NPAN 32
#define NACT 528          // NPAN*(NPAN+1)/2
#define NSTEPS 50
#define DTF 0.01f
#define WPITCH 67         // 32-bit words per LDS tile row (2 bf16 per word)

__device__ __forceinline__ float bf_lo(unsigned int w) {
  return __uint_as_float(w << 16);
}
__device__ __forceinline__ float bf_hi(unsigned int w) {
  return __uint_as_float(w & 0xFFFF0000u);
}
__device__ __forceinline__ unsigned short f2bf(float x) {
  unsigned int b = __float_as_uint(x);
  b += 0x7FFFu + ((b >> 16) & 1u);
  return (unsigned short)(b >> 16);
}
__device__ __forceinline__ int tri_offs(int bi) { return bi * (65 - bi) / 2; }

__global__ __launch_bounds__(256) void k_init(
    const float* __restrict__ phases, float* __restrict__ theta,
    float* __restrict__ svec, float* __restrict__ cvec) {
  int i = blockIdx.x * blockDim.x + threadIdx.x;
  if (i < NOSC) {
    float t = phases[i];
    theta[i] = t;
    svec[i] = sinf(t);
    cvec[i] = cosf(t);
  }
}

// Convert upper-tri 128x128 tiles of fp32 K into contiguous bf16 tiles.
__global__ __launch_bounds__(256) void k_convert(
    const float* __restrict__ Kmat, unsigned short* __restrict__ Kt) {
  int t = blockIdx.x;
  int bi = (int)((65.0f - sqrtf(4225.0f - 8.0f * (float)t)) * 0.5f);
  while (tri_offs(bi + 1) <= t) ++bi;
  while (tri_offs(bi) > t) --bi;
  const int bj = bi + (t - tri_offs(bi));

  const float* src = Kmat + (size_t)(bi * TILE) * NOSC + (size_t)(bj * TILE);
  unsigned short* dst = Kt + (size_t)t * (TILE * TILE);
  #pragma unroll
  for (int q = 0; q < 16; ++q) {
    const int idx = q * 256 + threadIdx.x;   // 0..4095 float4 units
    const int r = idx >> 5;                  // 32 float4 per row
    const int c = (idx & 31) << 2;
    const float4 f = *reinterpret_cast<const float4*>(src + (size_t)r * NOSC + c);
    ushort4 o;
    o.x = f2bf(f.x); o.y = f2bf(f.y); o.z = f2bf(f.z); o.w = f2bf(f.w);
    *reinterpret_cast<ushort4*>(dst + r * TILE + c) = o;
  }
}

// part layout: part[(slot*2 + field)*NOSC + i], field 0=S, 1=C.
__global__ __launch_bounds__(256, 4) void k_tiles(
    const unsigned short* __restrict__ Kt, const float* __restrict__ svec,
    const float* __restrict__ cvec, float* __restrict__ part) {
  __shared__ unsigned int tile_w[TILE * WPITCH];   // 34304 B
  __shared__ float2 rowf[TILE];                    // {sin,cos} of row range
  __shared__ float4 colf[TILE / 2];                // {s0,c0,s1,c1} col pairs
  __shared__ float4 colbuf[64];

  const int t = blockIdx.x;
  int bi = (int)((65.0f - sqrtf(4225.0f - 8.0f * (float)t)) * 0.5f);
  while (tri_offs(bi + 1) <= t) ++bi;
  while (tri_offs(bi) > t) --bi;
  const int bj = bi + (t - tri_offs(bi));
  const bool diag = (bi == bj);

  const int tid = threadIdx.x;
  const int lane = tid & 63;
  const int wv = tid >> 6;

  // stage s/c for both panels
  if (tid < 64) {
    const int c2 = tid;
    colf[c2] = make_float4(svec[bj * TILE + 2 * c2], cvec[bj * TILE + 2 * c2],
                           svec[bj * TILE + 2 * c2 + 1],
                           cvec[bj * TILE + 2 * c2 + 1]);
  } else if (tid < 192) {
    const int r = tid - 64;
    rowf[r] = make_float2(svec[bi * TILE + r], cvec[bi * TILE + r]);
  }

  // stage tile: contiguous 32 KB stream, 16B/lane; LDS pitch 67 words
  const unsigned short* g = Kt + (size_t)t * (TILE * TILE);
  #pragma unroll
  for (int q = 0; q < 8; ++q) {
    const int idx = q * 256 + tid;        // 0..2047 (16B units)
    const int r = idx >> 4;
    const int c8 = (idx & 15) << 3;       // ushort col, multiple of 8
    const uint4 u = *reinterpret_cast<const uint4*>(g + r * TILE + c8);
    unsigned int* dw = &tile_w[r * WPITCH + (c8 >> 1)];
    dw[0] = u.x; dw[1] = u.y; dw[2] = u.z; dw[3] = u.w;
  }
  __syncthreads();

  float aS0 = 0.f, aC0 = 0.f, aS1 = 0.f, aC1 = 0.f;
  if (wv < 2) {
    if (!diag) {
      // transpose dot: lane owns cols {2*lane, 2*lane+1}; wave wv rows wv*64..
      const int r0 = wv * 64;
      #pragma unroll 8
      for (int r = r0; r < r0 + 64; ++r) {
        const unsigned int w = tile_w[r * WPITCH + lane];  // 2-way max
        const float2 rf = rowf[r];                         // broadcast
        const float k0 = bf_lo(w), k1 = bf_hi(w);
        aS0 = fmaf(k0, rf.x, aS0); aC0 = fmaf(k0, rf.y, aC0);
        aS1 = fmaf(k1, rf.x, aS1); aC1 = fmaf(k1, rf.y, aC1);
      }
    }
  } else {
    // direct dot: lane owns row r; streams 64 word-cols
    const int r = (wv - 2) * 64 + lane;
    const unsigned int* tp = &tile_w[r * WPITCH];          // 2-way max
    #pragma unroll 8
    for (int c2 = 0; c2 < 64; ++c2) {
      const unsigned int w = tp[c2];
      const float4 cf = colf[c2];                          // broadcast
      const float k0 = bf_lo(w), k1 = bf_hi(w);
      aS0 = fmaf(k0, cf.x, aS0); aC0 = fmaf(k0, cf.y, aC0);
      aS0 = fmaf(k1, cf.z, aS0); aC0 = fmaf(k1, cf.w, aC0);
    }
  }

  if (wv == 0 && !diag) colbuf[lane] = make_float4(aS0, aC0, aS1, aC1);
  __syncthreads();

  if (wv == 1 && !diag) {
    // transpose partial -> slot bi of panel bj
    const float4 p = colbuf[lane];
    float* pS = part + ((size_t)bi * 2 + 0) * NOSC + bj * TILE;
    float* pC = part + ((size_t)bi * 2 + 1) * NOSC + bj * TILE;
    *reinterpret_cast<float2*>(pS + 2 * lane) =
        make_float2(p.x + aS0, p.z + aS1);
    *reinterpret_cast<float2*>(pC + 2 * lane) =
        make_float2(p.y + aC0, p.w + aC1);
  }
  if (wv >= 2) {
    // direct partial -> slot bj of panel bi
    const int r = (wv - 2) * 64 + lane;
    float* pS = part + ((size_t)bj * 2 + 0) * NOSC + bi * TILE;
    float* pC = part + ((size_t)bj * 2 + 1) * NOSC + bi * TILE;
    pS[r] = aS0;
    pC[r] = aC0;
  }
}

__global__ __launch_bounds__(256) void k_reduce(
    const float* __restrict__ part, const float* __restrict__ omegas,
    float* __restrict__ theta, float* __restrict__ svec,
    float* __restrict__ cvec) {
  const int i = blockIdx.x * blockDim.x + threadIdx.x;
  float aS = 0.f, aC = 0.f;
  #pragma unroll
  for (int s = 0; s < NPAN; ++s) {
    aS += part[((size_t)s * 2 + 0) * NOSC + i];
    aC += part[((size_t)s * 2 + 1) * NOSC + i];
  }
  const float si = svec[i];
  const float ci = cvec[i];
  const float th = theta[i] + DTF * (omegas[i] + ci * aS - si * aC);
  theta[i] = th;
  svec[i] = sinf(th);
  cvec[i] = cosf(th);
}

// ---- fallback (ws too small): fp32 full-matrix step, 2 rows/wave
__global__ __launch_bounds__(256, 2) void k_step_full(
    const float* __restrict__ Kf, const float* __restrict__ omegas,
    float* __restrict__ theta,
    const float* __restrict__ s_in, const float* __restrict__ c_in,
    float* __restrict__ s_out, float* __restrict__ c_out) {
  const int lane = threadIdx.x & 63;
  const int wave = threadIdx.x >> 6;
  const int row0 = (blockIdx.x << 3) + (wave << 1);
  const int row1 = row0 + 1;
  const float4* s4 = reinterpret_cast<const float4*>(s_in);
  const float4* c4 = reinterpret_cast<const float4*>(c_in);
  const float4* K40 = reinterpret_cast<const float4*>(Kf + (size_t)row0 * NOSC);
  const float4* K41 = reinterpret_cast<const float4*>(Kf + (size_t)row1 * NOSC);
  float aS0 = 0.f, aC0 = 0.f, aS1 = 0.f, aC1 = 0.f;
  #pragma unroll
  for (int ch = 0; ch < 16; ++ch) {
    const int idx = (ch << 6) + lane;
    float4 k0 = K40[idx], k1 = K41[idx], sv = s4[idx], cv = c4[idx];
    aS0 = fmaf(k0.x, sv.x, aS0); aS0 = fmaf(k0.y, sv.y, aS0);
    aS0 = fmaf(k0.z, sv.z, aS0); aS0 = fmaf(k0.w, sv.w, aS0);
    aC0 = fmaf(k0.x, cv.x, aC0); aC0 = fmaf(k0.y, cv.y, aC0);
    aC0 = fmaf(k0.z, cv.z, aC0); aC0 = fmaf(k0.w, cv.w, aC0);
    aS1 = fmaf(k1.x, sv.x, aS1); aS1 = fmaf(k1.y, sv.y, aS1);
    aS1 = fmaf(k1.z, sv.z, aS1); aS1 = fmaf(k1.w, sv.w, aS1);
    aC1 = fmaf(k1.x, cv.x, aC1); aC1 = fmaf(k1.y, cv.y, aC1);
    aC1 = fmaf(k1.z, cv.z, aC1); aC1 = fmaf(k1.w, cv.w, aC1);
  }
  #pragma unroll
  for (int off = 32; off > 0; off >>= 1) {
    aS0 += __shfl_xor(aS0, off); aC0 += __shfl_xor(aC0, off);
    aS1 += __shfl_xor(aS1, off); aC1 += __shfl_xor(aC1, off);
  }
  const int myRow = (lane == 0) ? row0 : ((lane == 1) ? row1 : -1);
  if (myRow >= 0) {
    const float accS = (lane == 0) ? aS0 : aS1;
    const float accC = (lane == 0) ? aC0 : aC1;
    const float tn = theta[myRow] +
        DTF * (omegas[myRow] + c_in[myRow] * accS - s_in[myRow] * accC);
    theta[myRow] = tn;
    s_out[myRow] = sinf(tn);
    c_out[myRow] = cosf(tn);
  }
}

extern "C" void kernel_launch(void* const* d_in, const int* in_sizes, int n_in,
                              void* d_out, int out_size, void* d_ws, size_t ws_size,
                              hipStream_t stream) {
  const float* phases = (const float*)d_in[0];
  const float* Kmat   = (const float*)d_in[1];
  const float* omegas = (const float*)d_in[2];
  float* out = (float*)d_out;

  float* ws = (float*)d_ws;
  float* theta = ws + 0 * NOSC;
  float* svec  = ws + 1 * NOSC;
  float* cvec  = ws + 2 * NOSC;
  float* part  = ws + 3 * NOSC;                 // 64*NOSC floats = 1 MiB

  const size_t headBytes = (size_t)(3 + 2 * NPAN) * NOSC * sizeof(float);
  const size_t ktOff = (headBytes + 255) & ~(size_t)255;
  const size_t ktBytes = (size_t)NACT * TILE * TILE * 2;   // 16.5 MiB
  const bool useTiles = (ws_size >= ktOff + ktBytes);
  unsigned short* Kt = (unsigned short*)((char*)d_ws + ktOff);

  k_init<<<NOSC / 256, 256, 0, stream>>>(phases, theta, svec, cvec);

  if (useTiles) {
    k_convert<<<NACT, 256, 0, stream>>>(Kmat, Kt);
    for (int t = 0; t < NSTEPS; ++t) {
      k_tiles<<<NACT, 256, 0, stream>>>(Kt, svec, cvec, part);
      k_reduce<<<NOSC / 256, 256, 0, stream>>>(part, omegas, theta, svec, cvec);
    }
  } else {
    float* sb[2] = {svec, part + 0 * NOSC};
    float* cb[2] = {cvec, part + 1 * NOSC};
    for (int t = 0; t < NSTEPS; ++t) {
      k_step_full<<<NOSC / 8, 256, 0, stream>>>(
          Kmat, omegas, theta, sb[t & 1], cb[t & 1], sb[(t + 1) & 1], cb[(t + 1) & 1]);
    }
  }
  hipMemcpyAsync(out, theta, NOSC * sizeof(float), hipMemcpyDeviceToDevice,
                 stream);
}

// Round 6
// 431.682 us; speedup vs baseline: 7.2133x; 1.0887x over previous
//
#include <hip/hip_runtime.h>
#include <math.h>

// Kuramoto Euler integration, N=4096, 50 steps, K symmetry, ONE kernel/step.
// coupling_i = cos(th_i)*(K@sin th)_i - sin(th_i)*(K@cos th)_i
// K -> bf16 upper-tri 128x128 tiles (528 tiles = 16.5 MiB/step).
// Step-k kernel: (phase 1) each block redundantly reconstructs theta_k and
// sin/cos for its two panels from part written by step k-1 (identical fp32
// op order in every block -> bit-identical); diag blocks persist theta_k.
// (phase 2) tile dots (direct + transpose) -> plain stores into disjoint
// slots of part[panel][slot][2][128]. Ping-pong part & theta buffers; no
// atomics, no fences; cross-launch visibility via stream ordering.

#define NOSC 4096
#define TILE 128
#define NPAN 32
#define NACT 528          // NPAN*(NPAN+1)/2
#define NSTEPS 50
#define DTF 0.01f
#define WPITCH 67         // 32-bit words per LDS tile row (2 bf16/word)
#define PARTN (NPAN * NPAN * 2 * TILE)   // floats per part buffer (1 MiB)

__device__ __forceinline__ float bf_lo(unsigned int w) {
  return __uint_as_float(w << 16);
}
__device__ __forceinline__ float bf_hi(unsigned int w) {
  return __uint_as_float(w & 0xFFFF0000u);
}
__device__ __forceinline__ unsigned short f2bf(float x) {
  unsigned int b = __float_as_uint(x);
  b += 0x7FFFu + ((b >> 16) & 1u);
  return (unsigned short)(b >> 16);
}
__device__ __forceinline__ int tri_offs(int bi) { return bi * (65 - bi) / 2; }
__device__ __forceinline__ void tile_decode(int t, int& bi, int& bj) {
  int b = (int)((65.0f - sqrtf(4225.0f - 8.0f * (float)t)) * 0.5f);
  while (tri_offs(b + 1) <= t) ++b;
  while (tri_offs(b) > t) --b;
  bi = b;
  bj = b + (t - tri_offs(b));
}

// Upper-tri 128x128 tiles of fp32 K -> contiguous bf16 tiles.
__global__ __launch_bounds__(256) void k_convert(
    const float* __restrict__ Kmat, unsigned short* __restrict__ Kt) {
  int bi, bj;
  tile_decode(blockIdx.x, bi, bj);
  const float* src = Kmat + (size_t)(bi * TILE) * NOSC + (size_t)(bj * TILE);
  unsigned short* dst = Kt + (size_t)blockIdx.x * (TILE * TILE);
  #pragma unroll
  for (int q = 0; q < 16; ++q) {
    const int idx = q * 256 + threadIdx.x;   // float4 units
    const int r = idx >> 5;
    const int c = (idx & 31) << 2;
    const float4 f = *reinterpret_cast<const float4*>(src + (size_t)r * NOSC + c);
    ushort4 o;
    o.x = f2bf(f.x); o.y = f2bf(f.y); o.z = f2bf(f.z); o.w = f2bf(f.w);
    *reinterpret_cast<ushort4*>(dst + r * TILE + c) = o;
  }
}

// part layout: part[(p*NPAN + s)*2*TILE + f*TILE + r]
template <bool FIRST>
__global__ __launch_bounds__(256, 4) void k_step(
    const unsigned short* __restrict__ Kt, const float* __restrict__ omegas,
    const float* __restrict__ thPrev, float* __restrict__ thNext,
    const float* __restrict__ partPrev, float* __restrict__ partNext) {
  __shared__ unsigned int tile_w[TILE * WPITCH];   // 34304 B
  __shared__ float2 rowf[TILE];                    // {sin,cos} row panel bi
  __shared__ float2 colf[TILE];                    // {sin,cos} col panel bj
  __shared__ float4 colbuf[64];

  int bi, bj;
  tile_decode(blockIdx.x, bi, bj);
  const bool diag = (bi == bj);
  const int tid = threadIdx.x;
  const int lane = tid & 63;
  const int wv = tid >> 6;

  // ---- issue tile loads early (32 KB contiguous) so they hide under phase 1
  const unsigned short* g = Kt + (size_t)blockIdx.x * (TILE * TILE);
  uint4 tb[8];
  #pragma unroll
  for (int q = 0; q < 8; ++q) {
    tb[q] = *reinterpret_cast<const uint4*>(g + (q * 256 + tid) * 8);
  }

  // ---- phase 1: reconstruct theta_k + sin/cos for this block's two panels.
  // Identical op order for a given panel in every block -> bit-identical.
  {
    const int half = tid >> 7;          // 0 -> panel bi (rows), 1 -> bj (cols)
    const int r = tid & 127;
    const int p = half ? bj : bi;
    const int i = p * TILE + r;
    float th = thPrev[i];
    if (!FIRST) {
      const float sp = sinf(th);
      const float cp = cosf(th);
      const float* pb = partPrev + ((size_t)p * NPAN) * (2 * TILE) + r;
      float aS = 0.f, aC = 0.f;
      #pragma unroll 8
      for (int s = 0; s < NPAN; ++s) {
        aS += pb[(size_t)s * (2 * TILE)];
        aC += pb[(size_t)s * (2 * TILE) + TILE];
      }
      th = th + DTF * (omegas[i] + cp * aS - sp * aC);
    }
    const float sn = sinf(th);
    const float cn = cosf(th);
    if (half == 0) {
      rowf[r] = make_float2(sn, cn);
      if (!FIRST && diag) thNext[i] = th;   // persist theta_k (once per panel)
    } else {
      colf[r] = make_float2(sn, cn);
    }
  }

  // ---- write staged tile into LDS (pitch 67 words)
  #pragma unroll
  for (int q = 0; q < 8; ++q) {
    const int idx = q * 256 + tid;
    const int r = idx >> 4;
    const int c8 = (idx & 15) << 3;
    unsigned int* dw = &tile_w[r * WPITCH + (c8 >> 1)];
    dw[0] = tb[q].x; dw[1] = tb[q].y; dw[2] = tb[q].z; dw[3] = tb[q].w;
  }
  __syncthreads();

  // ---- phase 2: tile dots
  float aS0 = 0.f, aC0 = 0.f, aS1 = 0.f, aC1 = 0.f;
  if (wv < 2) {
    if (!diag) {
      // transpose dot: lane owns cols {2*lane, 2*lane+1}; wave wv rows wv*64..
      const int r0 = wv * 64;
      #pragma unroll 8
      for (int r = r0; r < r0 + 64; ++r) {
        const unsigned int w = tile_w[r * WPITCH + lane];
        const float2 rf = rowf[r];
        const float k0 = bf_lo(w), k1 = bf_hi(w);
        aS0 = fmaf(k0, rf.x, aS0); aC0 = fmaf(k0, rf.y, aC0);
        aS1 = fmaf(k1, rf.x, aS1); aC1 = fmaf(k1, rf.y, aC1);
      }
    }
  } else {
    // direct dot: lane owns row r; streams 64 word-cols
    const int r = (wv - 2) * 64 + lane;
    const unsigned int* tp = &tile_w[r * WPITCH];
    #pragma unroll 8
    for (int c2 = 0; c2 < 64; ++c2) {
      const unsigned int w = tp[c2];
      const float2 cf0 = colf[2 * c2];
      const float2 cf1 = colf[2 * c2 + 1];
      aS0 = fmaf(bf_lo(w), cf0.x, aS0); aC0 = fmaf(bf_lo(w), cf0.y, aC0);
      aS0 = fmaf(bf_hi(w), cf1.x, aS0); aC0 = fmaf(bf_hi(w), cf1.y, aC0);
    }
  }

  if (wv == 0 && !diag) colbuf[lane] = make_float4(aS0, aC0, aS1, aC1);
  __syncthreads();

  if (wv == 1 && !diag) {
    // transpose partial -> part[bj][bi]
    const float4 p4 = colbuf[lane];
    float* pT = partNext + ((size_t)(bj * NPAN + bi) * 2) * TILE;
    *reinterpret_cast<float2*>(pT + 2 * lane) = make_float2(p4.x + aS0, p4.z + aS1);
    *reinterpret_cast<float2*>(pT + TILE + 2 * lane) = make_float2(p4.y + aC0, p4.w + aC1);
  }
  if (wv >= 2) {
    // direct partial -> part[bi][bj]
    const int r = (wv - 2) * 64 + lane;
    float* pD = partNext + ((size_t)(bi * NPAN + bj) * 2) * TILE;
    pD[r] = aS0;
    pD[TILE + r] = aC0;
  }
}

__global__ __launch_bounds__(256) void k_final(
    const float* __restrict__ thPrev, const float* __restrict__ partPrev,
    const float* __restrict__ omegas, float* __restrict__ out) {
  const int i = blockIdx.x * 256 + threadIdx.x;
  const int p = i >> 7;
  const int r = i & 127;
  const float th = thPrev[i];
  const float sp = sinf(th);
  const float cp = cosf(th);
  const float* pb = partPrev + ((size_t)p * NPAN) * (2 * TILE) + r;
  float aS = 0.f, aC = 0.f;
  #pragma unroll 8
  for (int s = 0; s < NPAN; ++s) {
    aS += pb[(size_t)s * (2 * TILE)];
    aC += pb[(size_t)s * (2 * TILE) + TILE];
  }
  out[i] = th + DTF * (omegas[i] + cp * aS - sp * aC);
}

// ---- fallback (ws too small): fp32 full-matrix step, 2 rows/wave
__global__ __launch_bounds__(256) void k_init_fb(
    const float* __restrict__ phases, float* __restrict__ theta,
    float* __restrict__ svec, float* __restrict__ cvec) {
  int i = blockIdx.x * blockDim.x + threadIdx.x;
  if (i < NOSC) {
    float t = phases[i];
    theta[i] = t;
    svec[i] = sinf(t);
    cvec[i] = cosf(t);
  }
}

__global__ __launch_bounds__(256, 2) void k_step_full(
    const float* __restrict__ Kf, const float* __restrict__ omegas,
    float* __restrict__ theta,
    const float* __restrict__ s_in, const float* __restrict__ c_in,
    float* __restrict__ s_out, float* __restrict__ c_out) {
  const int lane = threadIdx.x & 63;
  const int wave = threadIdx.x >> 6;
  const int row0 = (blockIdx.x << 3) + (wave << 1);
  const int row1 = row0 + 1;
  const float4* s4 = reinterpret_cast<const float4*>(s_in);
  const float4* c4 = reinterpret_cast<const float4*>(c_in);
  const float4* K40 = reinterpret_cast<const float4*>(Kf + (size_t)row0 * NOSC);
  const float4* K41 = reinterpret_cast<const float4*>(Kf + (size_t)row1 * NOSC);
  float aS0 = 0.f, aC0 = 0.f, aS1 = 0.f, aC1 = 0.f;
  #pragma unroll
  for (int ch = 0; ch < 16; ++ch) {
    const int idx = (ch << 6) + lane;
    float4 k0 = K40[idx], k1 = K41[idx], sv = s4[idx], cv = c4[idx];
    aS0 = fmaf(k0.x, sv.x, aS0); aS0 = fmaf(k0.y, sv.y, aS0);
    aS0 = fmaf(k0.z, sv.z, aS0); aS0 = fmaf(k0.w, sv.w, aS0);
    aC0 = fmaf(k0.x, cv.x, aC0); aC0 = fmaf(k0.y, cv.y, aC0);
    aC0 = fmaf(k0.z, cv.z, aC0); aC0 = fmaf(k0.w, cv.w, aC0);
    aS1 = fmaf(k1.x, sv.x, aS1); aS1 = fmaf(k1.y, sv.y, aS1);
    aS1 = fmaf(k1.z, sv.z, aS1); aS1 = fmaf(k1.w, sv.w, aS1);
    aC1 = fmaf(k1.x, cv.x, aC1); aC1 = fmaf(k1.y, cv.y, aC1);
    aC1 = fmaf(k1.z, cv.z, aC1); aC1 = fmaf(k1.w, cv.w, aC1);
  }
  #pragma unroll
  for (int off = 32; off > 0; off >>= 1) {
    aS0 += __shfl_xor(aS0, off); aC0 += __shfl_xor(aC0, off);
    aS1 += __shfl_xor(aS1, off); aC1 += __shfl_xor(aC1, off);
  }
  const int myRow = (lane == 0) ? row0 : ((lane == 1) ? row1 : -1);
  if (myRow >= 0) {
    const float accS = (lane == 0) ? aS0 : aS1;
    const float accC = (lane == 0) ? aC0 : aC1;
    const float tn = theta[myRow] +
        DTF * (omegas[myRow] + c_in[myRow] * accS - s_in[myRow] * accC);
    theta[myRow] = tn;
    s_out[myRow] = sinf(tn);
    c_out[myRow] = cosf(tn);
  }
}

extern "C" void kernel_launch(void* const* d_in, const int* in_sizes, int n_in,
                              void* d_out, int out_size, void* d_ws, size_t ws_size,
                              hipStream_t stream) {
  const float* phases = (const float*)d_in[0];
  const float* Kmat   = (const float*)d_in[1];
  const float* omegas = (const float*)d_in[2];
  float* out = (float*)d_out;

  float* ws = (float*)d_ws;
  float* thetaB[2] = {ws + 0 * NOSC, ws + 1 * NOSC};
  float* partB[2]  = {ws + 2 * NOSC, ws + 2 * NOSC + PARTN};

  const size_t headBytes = ((size_t)2 * NOSC + 2 * PARTN) * sizeof(float);
  const size_t ktOff = (headBytes + 255) & ~(size_t)255;
  const size_t ktBytes = (size_t)NACT * TILE * TILE * 2;   // 16.5 MiB
  const bool useTiles = (ws_size >= ktOff + ktBytes);
  unsigned short* Kt = (unsigned short*)((char*)d_ws + ktOff);

  if (useTiles) {
    k_convert<<<NACT, 256, 0, stream>>>(Kmat, Kt);
    for (int k = 0; k < NSTEPS; ++k) {
      const float* thP = (k <= 1) ? phases : thetaB[(k - 1) & 1];
      float* thN = thetaB[k & 1];
      const float* pP = partB[(k - 1) & 1];   // unused when k==0
      float* pN = partB[k & 1];
      if (k == 0) {
        k_step<true><<<NACT, 256, 0, stream>>>(Kt, omegas, thP, thN, pP, pN);
      } else {
        k_step<false><<<NACT, 256, 0, stream>>>(Kt, omegas, thP, thN, pP, pN);
      }
    }
    // theta_50 = theta_49 + dt*(omega + coupling_49)
    k_final<<<NOSC / 256, 256, 0, stream>>>(thetaB[(NSTEPS - 1) & 1],
                                            partB[(NSTEPS - 1) & 1], omegas, out);
  } else {
    float* theta = ws + 0 * NOSC;
    float* sb[2] = {ws + 1 * NOSC, ws + 3 * NOSC};
    float* cb[2] = {ws + 2 * NOSC, ws + 4 * NOSC};
    k_init_fb<<<NOSC / 256, 256, 0, stream>>>(phases, theta, sb[0], cb[0]);
    for (int t = 0; t < NSTEPS; ++t) {
      k_step_full<<<NOSC / 8, 256, 0, stream>>>(
          Kmat, omegas, theta, sb[t & 1], cb[t & 1], sb[(t + 1) & 1], cb[(t + 1) & 1]);
    }
    hipMemcpyAsync(out, theta, NOSC * sizeof(float), hipMemcpyDeviceToDevice,
                   stream);
  }
}